// Round 2
// baseline (368.222 us; speedup 1.0000x reference)
//
#include <hip/hip_runtime.h>

// FP32 bit-pulse -> FP8 E4M3 bit-pulse converter, wave-cooperative version.
//
// Layout problem: each value's 32 pulses are contiguous (128 B), so a
// thread-per-value mapping makes every load instruction stride 128 B across
// lanes (64 distinct lines / instr). Instead each WAVE processes 64 values:
//   - 8 rounds of fully-coalesced float4 loads (lane-contiguous, 1 KiB/instr)
//   - float4 pulses -> 4-bit nibble (exact: pulses are 0.0/1.0)
//   - 3-step __shfl_xor tree concatenates the 8 nibbles of each value
//     (groups of 8 lanes), MSB-first
//   - one bpermute per round gives lane l ownership of value l's word
//   - scalar E4M3 RNE conversion per lane -> output byte
//   - one bpermute per store round redistributes bytes so stores are
//     lane-contiguous float4 (perfectly coalesced)

__global__ __launch_bounds__(256) void fp8cvt_kernel(const float4* __restrict__ in,
                                                     float4* __restrict__ out,
                                                     int nvals) {
    const int tid  = blockIdx.x * blockDim.x + threadIdx.x;
    const int lane = tid & 63;
    const int wave = tid >> 6;
    const int vbase = wave * 64;            // first value this wave owns
    if (vbase >= nvals) return;             // nvals is a multiple of 64

    const float4* pin = in + (size_t)vbase * 8;   // 512 float4 per wave

    // ---- stage all 8 rounds of loads up front (MLP) ----
    float4 v[8];
#pragma unroll
    for (int r = 0; r < 8; ++r) v[r] = pin[r * 64 + lane];

    const int own_r = lane >> 3;            // round in which this lane grabs its word
    const int gsel  = (lane & 7) * 8;       // base lane of the group holding it

    unsigned myword = 0;
#pragma unroll
    for (int r = 0; r < 8; ++r) {
        // nibble: pulses 4m..4m+3 (m = lane&7) of value r*8 + lane/8, MSB first
        unsigned x = (unsigned)(v[r].x * 8.0f + v[r].y * 4.0f + v[r].z * 2.0f + v[r].w);
        unsigned y;
        y = __shfl_xor(x, 1);
        x = (lane & 1) ? ((y << 4)  | x) : ((x << 4)  | y);
        y = __shfl_xor(x, 2);
        x = (lane & 2) ? ((y << 8)  | x) : ((x << 8)  | y);
        y = __shfl_xor(x, 4);
        x = (lane & 4) ? ((y << 16) | x) : ((x << 16) | y);
        // every lane of group g = lane/8 now holds the word of value r*8+g
        unsigned sel = __shfl(x, gsel + r);   // word of value r*8 + (lane&7)
        if (r == own_r) myword = sel;         // lane l ends up with value l's word
    }

    // ---- E4M3 RNE conversion (one value per lane) ----
    unsigned s    = myword >> 31;
    int      exp  = (int)((myword >> 23) & 0xFF);
    unsigned mant = myword & 0x7FFFFFu;

    // normal path: exp8 = exp - 120, RNE 23 -> 3 mantissa bits
    unsigned kept  = mant >> 20;
    unsigned R     = (mant >> 19) & 1u;
    unsigned S     = (mant & ((1u << 19) - 1u)) != 0u;
    unsigned L     = kept & 1u;
    unsigned mr    = kept + (R & (S | L));
    unsigned carry = mr >> 3;
    unsigned mant_norm = carry ? 0u : (mr & 7u);
    int      exp_norm  = exp - 120 + (int)carry;

    // subnormal path (117 <= exp <= 120)
    unsigned full = (1u << 23) | mant;
    int sh = 141 - exp;
    sh = sh < 1 ? 1 : (sh > 24 ? 24 : sh);
    unsigned kept_s = full >> sh;
    unsigned Rs = (full >> (sh - 1)) & 1u;
    unsigned Ss = (full & ((1u << (sh - 1)) - 1u)) != 0u;
    unsigned Ls = kept_s & 1u;
    unsigned ms = kept_s + (Rs & (Ss | Ls));
    unsigned sub_of   = (ms >= 8u);
    unsigned sub_exp  = sub_of ? 1u : 0u;
    unsigned sub_mant = sub_of ? 0u : ms;

    int exp8, mant8;
    if (exp > 134)                      { exp8 = 15;            mant8 = 6; }
    else if (exp >= 117 && exp <= 120)  { exp8 = (int)sub_exp;  mant8 = (int)sub_mant; }
    else if (exp < 117)                 { exp8 = 0;             mant8 = 0; }
    else                                { exp8 = exp_norm;      mant8 = (int)mant_norm; }

    unsigned byte = (s << 7) | ((unsigned)exp8 << 3) | (unsigned)mant8;

    // ---- coalesced output: 128 float4 per wave, 2 store rounds ----
    float4* pout = out + (size_t)vbase * 2;
#pragma unroll
    for (int r2 = 0; r2 < 2; ++r2) {
        // float4 index f = r2*64 + lane covers value r2*32 + lane/2,
        // bits starting at 4*(lane&1) from the top of the byte
        unsigned b = __shfl(byte, r2 * 32 + (lane >> 1));
        int hi = (lane & 1) ? 3 : 7;
        float4 o;
        o.x = (float)((b >> hi)       & 1);
        o.y = (float)((b >> (hi - 1)) & 1);
        o.z = (float)((b >> (hi - 2)) & 1);
        o.w = (float)((b >> (hi - 3)) & 1);
        pout[r2 * 64 + lane] = o;
    }
}

extern "C" void kernel_launch(void* const* d_in, const int* in_sizes, int n_in,
                              void* d_out, int out_size, void* d_ws, size_t ws_size,
                              hipStream_t stream) {
    const float4* in  = (const float4*)d_in[0];
    float4*       out = (float4*)d_out;
    int nvals = in_sizes[0] / 32;           // number of FP32 values (2,097,152)
    int block = 256;                        // 4 waves/block, 64 values/wave
    int grid  = (nvals + 4 * 64 - 1) / (4 * 64);
    fp8cvt_kernel<<<grid, block, 0, stream>>>(in, out, nvals);
}